// Round 1
// baseline (309.138 us; speedup 1.0000x reference)
//
#include <hip/hip_runtime.h>
#include <math.h>

// Router: x (4,8192,1024) f32, W (64,1024) f32
// out = [ top_idx (32768,2) as float | top_gates (32768,2) | loss (1) ]  => 131073 floats
// ws  = 64 floats of per-expert prob sums (atomic accumulated)

constexpr int DMODEL = 1024;
constexpr int NEXP   = 64;
constexpr int BM     = 64;    // tokens per workgroup
constexpr int BK     = 64;    // K per staging tile
constexpr int EPW    = 16;    // experts per wave
constexpr int NWAVE  = 4;
constexpr int NTOK   = 32768;

__global__ __launch_bounds__(256, 2) void router_kernel(
    const float* __restrict__ x, const float* __restrict__ W,
    float* __restrict__ out, float* __restrict__ expert_sums)
{
    // x tile, XOR-swizzled: element (token t, k-chunk c, j) lives at xs[c][t ^ (c&7)][j]
    __shared__ __align__(16) float xs[BK / 4][BM][4];
    __shared__ float lmax[NWAVE][BM];
    __shared__ float lsum[NWAVE][BM];
    __shared__ float ltv[NWAVE][BM][2];
    __shared__ int   lti[NWAVE][BM][2];

    const int tid  = threadIdx.x;
    const int lane = tid & 63;
    const int w    = __builtin_amdgcn_readfirstlane(tid >> 6);  // wave id, uniform
    const int tok0 = blockIdx.x * BM;

    // wave w owns experts [w*16, w*16+16) — W accessed via uniform (scalar) loads
    const float* Wb = W + (size_t)w * EPW * DMODEL;

    float4 acc[EPW];
#pragma unroll
    for (int e = 0; e < EPW; ++e) acc[e] = make_float4(0.f, 0.f, 0.f, 0.f);

    for (int k0 = 0; k0 < DMODEL; k0 += BK) {
        __syncthreads();
        // stage x[tok0..tok0+63][k0..k0+63] into LDS, coalesced, swizzled
#pragma unroll
        for (int it = 0; it < (BM * BK / 4) / 256; ++it) {
            int idx = it * 256 + tid;
            int t = idx >> 4;      // 16 float4-chunks per token row
            int c = idx & 15;
            float4 v = *reinterpret_cast<const float4*>(
                x + (size_t)(tok0 + t) * DMODEL + k0 + c * 4);
            *reinterpret_cast<float4*>(&xs[c][t ^ (c & 7)][0]) = v;
        }
        __syncthreads();

#pragma unroll 2
        for (int c = 0; c < BK / 4; ++c) {
            float4 xv = *reinterpret_cast<const float4*>(&xs[c][lane ^ (c & 7)][0]);
            const float* wp0 = Wb + k0 + c * 4;
#pragma unroll
            for (int e = 0; e < EPW; ++e) {
                const float* wp = wp0 + (size_t)e * DMODEL;  // uniform -> s_load
                acc[e].x = fmaf(xv.x, wp[0], acc[e].x);
                acc[e].y = fmaf(xv.y, wp[1], acc[e].y);
                acc[e].z = fmaf(xv.z, wp[2], acc[e].z);
                acc[e].w = fmaf(xv.w, wp[3], acc[e].w);
            }
        }
    }

    // ---- epilogue ----
    float logit[EPW];
    float lm = -INFINITY;
#pragma unroll
    for (int e = 0; e < EPW; ++e) {
        logit[e] = (acc[e].x + acc[e].y) + (acc[e].z + acc[e].w);
        lm = fmaxf(lm, logit[e]);
    }
    lmax[w][lane] = lm;
    __syncthreads();
    const float gmax = fmaxf(fmaxf(lmax[0][lane], lmax[1][lane]),
                             fmaxf(lmax[2][lane], lmax[3][lane]));

    // local top-2, total order: value desc, index asc (matches lax.top_k stability)
    float v0 = -INFINITY, v1 = -INFINITY;
    int   i0 = NEXP, i1 = NEXP;
#pragma unroll
    for (int e = 0; e < EPW; ++e) {
        float v = logit[e];
        int  gi = w * EPW + e;
        if (v > v0) { v1 = v0; i1 = i0; v0 = v; i0 = gi; }
        else if (v > v1) { v1 = v; i1 = gi; }
    }

    float p[EPW];
    float s = 0.f;
#pragma unroll
    for (int e = 0; e < EPW; ++e) { p[e] = __expf(logit[e] - gmax); s += p[e]; }

    lsum[w][lane] = s;
    ltv[w][lane][0] = v0; ltv[w][lane][1] = v1;
    lti[w][lane][0] = i0; lti[w][lane][1] = i1;
    __syncthreads();

    const float gsum = (lsum[0][lane] + lsum[1][lane]) + (lsum[2][lane] + lsum[3][lane]);
    const float inv  = 1.0f / gsum;

    // per-expert prob sums over this WG's 64 tokens -> one atomic per (wave, expert)
#pragma unroll
    for (int e = 0; e < EPW; ++e) {
        float v = p[e] * inv;
#pragma unroll
        for (int off = 32; off; off >>= 1) v += __shfl_xor(v, off, 64);
        if (lane == 0) atomicAdd(&expert_sums[w * EPW + e], v);
    }

    // wave 0 merges the 4 waves' top-2 candidates and writes idx + gates
    if (tid < 64) {
        const int l = tid;
        float bv0 = -INFINITY, bv1 = -INFINITY;
        int   bi0 = NEXP, bi1 = NEXP;
#pragma unroll
        for (int ww = 0; ww < NWAVE; ++ww) {
#pragma unroll
            for (int j = 0; j < 2; ++j) {
                float v  = ltv[ww][l][j];
                int   gi = lti[ww][l][j];
                bool b0 = (v > bv0) || (v == bv0 && gi < bi0);
                if (b0) { bv1 = bv0; bi1 = bi0; bv0 = v; bi0 = gi; }
                else {
                    bool b1 = (v > bv1) || (v == bv1 && gi < bi1);
                    if (b1) { bv1 = v; bi1 = gi; }
                }
            }
        }
        float g     = __expf(bv1 - bv0);
        float denom = 1.0f + g;
        float g0 = 1.0f / denom;
        float g1 = g / denom;

        size_t tok = (size_t)tok0 + l;
        reinterpret_cast<float2*>(out)[tok]              = make_float2((float)bi0, (float)bi1);
        reinterpret_cast<float2*>(out + 2 * NTOK)[tok]   = make_float2(g0, g1);
    }
}

__global__ void loss_kernel(const float* __restrict__ sums, float* __restrict__ out)
{
    const int lane = threadIdx.x;  // 64 threads
    float pv = sums[lane] * (1.0f / (float)NTOK);  // avg_probs[lane]
    float m = pv;
#pragma unroll
    for (int off = 32; off; off >>= 1) m += __shfl_xor(m, off, 64);
    m *= (1.0f / (float)NEXP);
    float d = pv - m;
    float v = d * d;
#pragma unroll
    for (int off = 32; off; off >>= 1) v += __shfl_xor(v, off, 64);
    v *= (1.0f / (float)(NEXP - 1));  // ddof=1
    if (lane == 0) {
        float stdv = sqrtf(v);
        float r = stdv / (m + 1e-6f);
        out[4 * NTOK] = r * r;
    }
}

extern "C" void kernel_launch(void* const* d_in, const int* in_sizes, int n_in,
                              void* d_out, int out_size, void* d_ws, size_t ws_size,
                              hipStream_t stream)
{
    const float* x = (const float*)d_in[0];
    const float* W = (const float*)d_in[1];
    float* out  = (float*)d_out;
    float* sums = (float*)d_ws;

    hipMemsetAsync(d_ws, 0, NEXP * sizeof(float), stream);

    hipLaunchKernelGGL(router_kernel, dim3(NTOK / BM), dim3(256), 0, stream,
                       x, W, out, sums);
    hipLaunchKernelGGL(loss_kernel, dim3(1), dim3(64), 0, stream, sums, out);
}